// Round 8
// baseline (219.621 us; speedup 1.0000x reference)
//
#include <hip/hip_runtime.h>
#include <hip/hip_bf16.h>

typedef __attribute__((ext_vector_type(8))) short short8;
typedef __attribute__((ext_vector_type(4))) float f32x4;
typedef __attribute__((ext_vector_type(2))) unsigned int u32x2;
typedef __attribute__((ext_vector_type(4))) unsigned int u32x4;

#define SLAB 9216      // bytes per slot slab: 144 rows x 64B (32 bf16)
#define BUFB 18432     // per-step buffer: 2 slots

// involution swizzle: XOR bank-group bits (4-5) with row bits (7-8)
__device__ __forceinline__ unsigned sw(unsigned off) {
  return off ^ (((off >> 7) & 3u) << 4);
}

__device__ __forceinline__ unsigned pk2(float lo, float hi) {
  union { __hip_bfloat162 h; unsigned u; } c;
  c.h = __float22bfloat162_rn(float2{lo, hi});
  return c.u;
}

// one-time: ker (fp32, N*K x F x C) -> bf16 fragment-linear in ws
// frag(ch,nk,ft,lane) holds W[f=ft*16+(lane&15), c=ch*32+(lane>>4)*8 .. +8]
extern "C" __global__ void w_prep(const float* __restrict__ ker, u32x4* __restrict__ wsw) {
  const int nk = blockIdx.x % 36;
  const int ch = blockIdx.x / 36;
  const int lane = threadIdx.x & 63;
  const int ft = threadIdx.x >> 6;
  const float* src = ker + (size_t)(nk * 64 + ft * 16 + (lane & 15)) * 64
                         + ch * 32 + (lane >> 4) * 8;
  f32x4 a0 = *(const f32x4*)src;
  f32x4 a1 = *(const f32x4*)(src + 4);
  u32x4 h = { pk2(a0.x, a0.y), pk2(a0.z, a0.w), pk2(a1.x, a1.y), pk2(a1.z, a1.w) };
  wsw[((ch * 36 + nk) * 4 + ft) * 64 + lane] = h;
}

// one k-iteration: issue replacement W loads (window KK+2), 2 B ds_reads,
// setprio-wrapped 8-MFMA cluster, rotate window.
#define KSTEP(KK, WREG, S2, K2) do {                                           \
    const int _wo = (((S2) & 1) * 9216) + (((S2) >> 1) * 2304) + ((K2) * 256); \
    short8 _n0 = wqb[_wo];                                                     \
    short8 _n1 = wqb[_wo + 64];                                                \
    short8 _n2 = wqb[_wo + 128];                                               \
    short8 _n3 = wqb[_wo + 192];                                               \
    const unsigned _kq = cb + (unsigned)(((KK) >> 2) * 512) + poff[(KK) & 3];  \
    short8 _b0 = *(const short8*)(xs + _kq);                                   \
    short8 _b1 = *(const short8*)(xs + _kq + 1024u);                           \
    __builtin_amdgcn_s_setprio(1);                                             \
    acc[0][0] = __builtin_amdgcn_mfma_f32_16x16x32_bf16(WREG[0], _b0, acc[0][0], 0, 0, 0); \
    acc[1][0] = __builtin_amdgcn_mfma_f32_16x16x32_bf16(WREG[1], _b0, acc[1][0], 0, 0, 0); \
    acc[2][0] = __builtin_amdgcn_mfma_f32_16x16x32_bf16(WREG[2], _b0, acc[2][0], 0, 0, 0); \
    acc[3][0] = __builtin_amdgcn_mfma_f32_16x16x32_bf16(WREG[3], _b0, acc[3][0], 0, 0, 0); \
    acc[0][1] = __builtin_amdgcn_mfma_f32_16x16x32_bf16(WREG[0], _b1, acc[0][1], 0, 0, 0); \
    acc[1][1] = __builtin_amdgcn_mfma_f32_16x16x32_bf16(WREG[1], _b1, acc[1][1], 0, 0, 0); \
    acc[2][1] = __builtin_amdgcn_mfma_f32_16x16x32_bf16(WREG[2], _b1, acc[2][1], 0, 0, 0); \
    acc[3][1] = __builtin_amdgcn_mfma_f32_16x16x32_bf16(WREG[3], _b1, acc[3][1], 0, 0, 0); \
    __builtin_amdgcn_s_setprio(0);                                             \
    WREG[0] = _n0; WREG[1] = _n1; WREG[2] = _n2; WREG[3] = _n3;                \
  } while (0)

extern "C" __global__ __launch_bounds__(512, 4)
void glc_mfma(const float* __restrict__ x, const short8* __restrict__ wsw,
              const int* __restrict__ nb, float* __restrict__ out) {
  __shared__ __align__(16) char xs[2 * BUFB];

  const int bid = blockIdx.x;
  const int tt = bid % 5;
  const int up = (bid / 5) % 13;
  const int a  = (bid / 65) % 3;
  const int b  = bid / 195;
  const int t0 = tt * 64;
  const int u0 = up * 2;
  const bool updup = (up == 12);   // u-pair (24,24): odd waves duplicate

  const int tid  = threadIdx.x;
  const int lane = tid & 63;
  const int wave = tid >> 6;           // 0..7
  const int uloc = wave & 1;           // which u of the pair
  const int tp   = wave >> 1;          // which tile-pair (2 col-tiles) of the u-slot

  const int su0 = u0;
  const int su1 = updup ? u0 : (u0 + 1);

  const int rl = lane & 15, gq = lane >> 4;
  unsigned poff[4];
#pragma unroll
  for (int m = 0; m < 4; ++m)
    poff[m] = sw((unsigned)((2 * m + rl) * 64 + gq * 16));

  f32x4 acc[4][2];
#pragma unroll
  for (int j = 0; j < 4; ++j)
#pragma unroll
    for (int i = 0; i < 2; ++i) acc[j][i] = (f32x4){0.f, 0.f, 0.f, 0.f};

  // ---- per-thread staging load offsets (computed once; write offsets recomputed) ----
  int goff[5];
#pragma unroll
  for (int j = 0; j < 5; ++j) {
    const int u = j * 512 + tid;
    const int slot = (u >= 1152) ? 1 : 0;
    const int rem = u - slot * 1152;
    const int r = rem >> 3, q = rem & 7;
    int t = t0 + (r >> 1); if (t > 299) t = 299;   // clamp; garbage discarded
    goff[j] = t * 9600 + (r & 1) * 64 + q * 4;     // x fp32 offset (v,ch terms per step)
  }
  const float* xb = x + (size_t)b * (300 * 9600) + (size_t)a * 3200;
  const short8* wqb = wsw + lane;

  f32x4 sr[5];
  auto stage_load = [&](int snx) {
    const int n2 = snx >> 1, ch2 = snx & 1;
    const int add0 = nb[su0 * 4 + n2] * 128 + ch2 * 32;
    const int add1 = nb[su1 * 4 + n2] * 128 + ch2 * 32;
#pragma unroll
    for (int j = 0; j < 5; ++j)
      if (j < 4 || tid < 256) {
        const bool hi = (j * 512 + tid) >= 1152;
        sr[j] = *(const f32x4*)(xb + goff[j] + (hi ? add1 : add0));
      }
  };
  auto stage_write = [&](int snx) {
    char* dst = xs + (snx & 1) * BUFB;
#pragma unroll
    for (int j = 0; j < 5; ++j)
      if (j < 4 || tid < 256) {
        const int u = j * 512 + tid;
        const int slot = (u >= 1152) ? 1 : 0;
        const int rem = u - slot * 1152;
        const int r = rem >> 3, q = rem & 7;
        u32x2 h = { pk2(sr[j].x, sr[j].y), pk2(sr[j].z, sr[j].w) };
        *(u32x2*)(dst + slot * SLAB + sw((unsigned)(r * 64 + q * 8))) = h;
      }
  };

  // ---- prologue: W(0, k=0..1) into 2-deep window; stage step 0 ----
  short8 wA[4], wB[4];
#pragma unroll
  for (int j = 0; j < 4; ++j) { wA[j] = wqb[j * 64]; wB[j] = wqb[256 + j * 64]; }
  stage_load(0);
  stage_write(0);
  __syncthreads();

  const unsigned cb0 = (unsigned)(uloc * SLAB + tp * 2048);

  // ---- main loop: 4 double-steps; window parity static per body ----
#pragma unroll 1
  for (int sh = 0; sh < 4; ++sh) {
    const int s = 2 * sh, s1 = s + 1;
    const int s2 = (sh < 3) ? (s + 2) : 7;     // sh=3: dummy in-bounds reloads
    // ---- even step s (window: k even->wA) ----
    {
      stage_load(s1);
      const unsigned cb = cb0;
      KSTEP(0, wA, s, 2);  KSTEP(1, wB, s, 3);  KSTEP(2, wA, s, 4);
      KSTEP(3, wB, s, 5);  KSTEP(4, wA, s, 6);  KSTEP(5, wB, s, 7);
      KSTEP(6, wA, s, 8);  KSTEP(7, wB, s1, 0); KSTEP(8, wA, s1, 1);
      stage_write(s1);
      __syncthreads();
    }
    // ---- odd step s1 (window: k even->wB) ----
    {
      if (sh < 3) stage_load(s + 2);
      const unsigned cb = cb0 + BUFB;
      KSTEP(0, wB, s1, 2); KSTEP(1, wA, s1, 3); KSTEP(2, wB, s1, 4);
      KSTEP(3, wA, s1, 5); KSTEP(4, wB, s1, 6); KSTEP(5, wA, s1, 7);
      KSTEP(6, wB, s1, 8); KSTEP(7, wA, s2, 0); KSTEP(8, wB, s2, 1);
      if (sh < 3) {
        stage_write(s + 2);
        __syncthreads();
      }
    }
  }

  // ---- epilogue: tile (tp*2+i): col = tile*16+rl; f = ft*16 + gq*4 + reg ----
  if (updup && uloc) return;            // skip duplicate u=24 stores
  const int u = u0 + uloc;
  const f32x4 z4 = (f32x4){0.f, 0.f, 0.f, 0.f};
#pragma unroll
  for (int i = 0; i < 2; ++i) {
    const int col = (tp * 2 + i) * 16 + rl;   // 0..127 within u-slot (t-rel, p-minor)
    const int t = t0 + (col >> 1);
    const int p = col & 1;
    if (t < 300) {
      float* dst = out + ((size_t)((b * 300 + t) * 3 + a) * 50 + (u * 2 + p)) * 64 + gq * 4;
      const bool valid = (t < 292);     // t>=292: zero-pad tail
#pragma unroll
      for (int ft = 0; ft < 4; ++ft) {
        f32x4 v = valid ? acc[ft][i] : z4;
        *(f32x4*)(dst + ft * 16) = v;
      }
    }
  }
}

extern "C" void kernel_launch(void* const* d_in, const int* in_sizes, int n_in,
                              void* d_out, int out_size, void* d_ws, size_t ws_size,
                              hipStream_t stream) {
  const float* x   = (const float*)d_in[0];
  const float* ker = (const float*)d_in[1];
  const int*   nb  = (const int*)d_in[2];
  float* out = (float*)d_out;

  w_prep<<<dim3(72), dim3(256), 0, stream>>>(ker, (u32x4*)d_ws);
  glc_mfma<<<dim3(8 * 3 * 13 * 5), dim3(512), 0, stream>>>(x, (const short8*)d_ws, nb, out);
}